// Round 4
// baseline (149.184 us; speedup 1.0000x reference)
//
#include <hip/hip_runtime.h>
#include <hip/hip_bf16.h>
#include <math.h>

// Output layout (float32, concatenated in reference return order):
//   rendered [128,1,28,28]  @ 0       (100352)
//   mu       [128,64]       @ 100352  (8192)
//   logvar   [128,64]       @ 108544  (8192)
//   cp       [128,2,3,4,2]  @ 116736  (6144)
//   widths   [128,2]        @ 122880  (256)
//   alphas   [128,2]        @ 123136  (256)
#define REND_OFF 0
#define MU_OFF   100352
#define LV_OFF   108544
#define CP_OFF   116736
#define W_OFF    122880
#define A_OFF    123136

// bf16 weight workspace layout (element offsets; all row-major [K][N]):
#define WS_W1 0         //  [784][256]
#define WS_W2 200704    //  [256][256]
#define WS_ML 266240    //  [256][128]  (mu|lv)
#define WS_D1 299008    //  [64][512]
#define WS_D2 331776    //  [512][512]
#define WS_H  593920    //  [512][64]   (p|wd|a|pad0)
#define WS_TOT 626688   //  = 1.25 MB bf16

// fp32 activation buffers in d_ws, placed after the bf16 weights
// (WS_TOT*2 = 1253376 bytes, 16B aligned).
#define AF_H1 0         // [128][256]
#define AF_H2 32768     // [128][256]
#define AF_Z  65536     // [128][64]
#define AF_D1 73728     // [128][512]
#define AF_D2 139264    // [128][512]

__device__ __forceinline__ float leakyf(float x) {
    return x >= 0.f ? x : 0.2f * x;
}
__device__ __forceinline__ float seluf(float x) {
    const float sc = 1.0507009873554805f;
    const float al = 1.6732632423543772f;
    return x > 0.f ? sc * x : sc * al * expm1f(x);
}
__device__ __forceinline__ float sigmoidf(float x) {
    return 1.f / (1.f + expf(-x));
}
__device__ __forceinline__ void bf2(unsigned u, float& lo, float& hi) {
    lo = __uint_as_float(u << 16);
    hi = __uint_as_float(u & 0xffff0000u);
}

// ---- kernel 0: convert fp32 weights -> bf16 workspace (fused/padded) ----
__global__ __launch_bounds__(256) void conv_w(
    const float* __restrict__ e_w1, const float* __restrict__ e_w2,
    const float* __restrict__ w_mu, const float* __restrict__ w_lv,
    const float* __restrict__ d_w1, const float* __restrict__ d_w2,
    const float* __restrict__ p_w,  const float* __restrict__ wd_w,
    const float* __restrict__ a_w,  __hip_bfloat16* __restrict__ ws)
{
    int i = blockIdx.x * 256 + threadIdx.x;
    if (i >= WS_TOT) return;
    float v;
    if (i < WS_W2) v = e_w1[i];
    else if (i < WS_ML) v = e_w2[i - WS_W2];
    else if (i < WS_D1) {
        int r = i - WS_ML, k = r >> 7, u = r & 127;
        v = (u < 64) ? w_mu[k * 64 + u] : w_lv[k * 64 + u - 64];
    }
    else if (i < WS_D2) v = d_w1[i - WS_D1];
    else if (i < WS_H)  v = d_w2[i - WS_D2];
    else {
        int r = i - WS_H, k = r >> 6, u = r & 63;
        v = (u < 40) ? p_w[k * 40 + u]
          : (u < 42) ? wd_w[k * 2 + u - 40]
          : (u < 44) ? a_w[k * 2 + u - 42] : 0.f;
    }
    ws[i] = (__hip_bfloat16)v;
}

// ---- generic layer GEMM: C[128,N] = act(A[128,K] @ Wbf16[K,N] + bias) ----
// grid (N/NT, 128/BT), 256 threads. Thread: jg = cols group (4 cols via
// uint2), ks = k-slice. A-tile staged to LDS interleaved [k][b] so one
// broadcast ds_read_b128 serves all 4 batch rows. Padded LDS slice reduce.
template<int K, int N, int NT, int ACT>
__global__ __launch_bounds__(256) void gemm_act(
    const float* __restrict__ A, const __hip_bfloat16* __restrict__ Wb,
    const float* __restrict__ bias, float* __restrict__ C)
{
    constexpr int BT  = 4;
    constexpr int JG  = NT / 4;      // col groups
    constexpr int S   = 256 / JG;    // k slices
    constexpr int Ks  = K / S;
    constexpr int NTp = NT + 4;
    static_assert(BT * NT == 256, "epilogue mapping");
    static_assert(S * Ks == K, "k split");

    const int tid = threadIdx.x;
    const int b0  = blockIdx.y * BT;
    const int nb  = blockIdx.x;

    __shared__ __align__(16) float Atile[BT * K];
    __shared__ __align__(16) float red[BT * S * NTp];

    for (int i = tid; i < BT * K; i += 256) {
        int b = i / K, k = i - b * K;
        Atile[k * BT + b] = A[(b0 + b) * K + k];
    }
    __syncthreads();

    {
        const int jg = tid % JG, ks = tid / JG;
        const int col0 = nb * NT + 4 * jg;
        const uint2* wp = (const uint2*)Wb + (ks * Ks) * (N / 4) + (col0 >> 2);
        const float4* xp = (const float4*)Atile + ks * Ks;
        float a00=0,a01=0,a02=0,a03=0, a10=0,a11=0,a12=0,a13=0;
        float a20=0,a21=0,a22=0,a23=0, a30=0,a31=0,a32=0,a33=0;
        #pragma unroll 4
        for (int kk = 0; kk < Ks; ++kk) {
            uint2 w = wp[kk * (N / 4)];
            float w0,w1,w2,w3; bf2(w.x,w0,w1); bf2(w.y,w2,w3);
            float4 xv = xp[kk];
            a00 = fmaf(xv.x,w0,a00); a01 = fmaf(xv.x,w1,a01);
            a02 = fmaf(xv.x,w2,a02); a03 = fmaf(xv.x,w3,a03);
            a10 = fmaf(xv.y,w0,a10); a11 = fmaf(xv.y,w1,a11);
            a12 = fmaf(xv.y,w2,a12); a13 = fmaf(xv.y,w3,a13);
            a20 = fmaf(xv.z,w0,a20); a21 = fmaf(xv.z,w1,a21);
            a22 = fmaf(xv.z,w2,a22); a23 = fmaf(xv.z,w3,a23);
            a30 = fmaf(xv.w,w0,a30); a31 = fmaf(xv.w,w1,a31);
            a32 = fmaf(xv.w,w2,a32); a33 = fmaf(xv.w,w3,a33);
        }
        *(float4*)&red[(0 * S + ks) * NTp + 4 * jg] = make_float4(a00,a01,a02,a03);
        *(float4*)&red[(1 * S + ks) * NTp + 4 * jg] = make_float4(a10,a11,a12,a13);
        *(float4*)&red[(2 * S + ks) * NTp + 4 * jg] = make_float4(a20,a21,a22,a23);
        *(float4*)&red[(3 * S + ks) * NTp + 4 * jg] = make_float4(a30,a31,a32,a33);
    }
    __syncthreads();

    {
        int b = tid / NT, j = tid % NT;
        float s = bias[nb * NT + j];
        #pragma unroll
        for (int si = 0; si < S; ++si) s += red[(b * S + si) * NTp + j];
        s = (ACT == 1) ? leakyf(s) : seluf(s);
        C[(b0 + b) * N + nb * NT + j] = s;
    }
}

// ---- mu|logvar head (K=256, N=128) + reparameterization, writes z ----
__global__ __launch_bounds__(256) void gemm_ml(
    const float* __restrict__ A, const __hip_bfloat16* __restrict__ Wb,
    const float* __restrict__ b_mu, const float* __restrict__ b_lv,
    const float* __restrict__ eps, float* __restrict__ out,
    float* __restrict__ Z)
{
    constexpr int K = 256, N = 128, JG = 32, S = 8, Ks = 32, NTp = 132, BT = 4;
    const int tid = threadIdx.x;
    const int b0  = blockIdx.x * BT;

    __shared__ __align__(16) float Atile[BT * K];
    __shared__ __align__(16) float red[BT * S * NTp];
    __shared__ float ml[BT][128];

    for (int i = tid; i < BT * K; i += 256) {
        int b = i / K, k = i - b * K;
        Atile[k * BT + b] = A[(b0 + b) * K + k];
    }
    __syncthreads();

    {
        const int jg = tid % JG, ks = tid / JG;
        const uint2* wp = (const uint2*)Wb + (ks * Ks) * (N / 4) + jg;
        const float4* xp = (const float4*)Atile + ks * Ks;
        float a00=0,a01=0,a02=0,a03=0, a10=0,a11=0,a12=0,a13=0;
        float a20=0,a21=0,a22=0,a23=0, a30=0,a31=0,a32=0,a33=0;
        #pragma unroll 4
        for (int kk = 0; kk < Ks; ++kk) {
            uint2 w = wp[kk * (N / 4)];
            float w0,w1,w2,w3; bf2(w.x,w0,w1); bf2(w.y,w2,w3);
            float4 xv = xp[kk];
            a00 = fmaf(xv.x,w0,a00); a01 = fmaf(xv.x,w1,a01);
            a02 = fmaf(xv.x,w2,a02); a03 = fmaf(xv.x,w3,a03);
            a10 = fmaf(xv.y,w0,a10); a11 = fmaf(xv.y,w1,a11);
            a12 = fmaf(xv.y,w2,a12); a13 = fmaf(xv.y,w3,a13);
            a20 = fmaf(xv.z,w0,a20); a21 = fmaf(xv.z,w1,a21);
            a22 = fmaf(xv.z,w2,a22); a23 = fmaf(xv.z,w3,a23);
            a30 = fmaf(xv.w,w0,a30); a31 = fmaf(xv.w,w1,a31);
            a32 = fmaf(xv.w,w2,a32); a33 = fmaf(xv.w,w3,a33);
        }
        *(float4*)&red[(0 * S + ks) * NTp + 4 * jg] = make_float4(a00,a01,a02,a03);
        *(float4*)&red[(1 * S + ks) * NTp + 4 * jg] = make_float4(a10,a11,a12,a13);
        *(float4*)&red[(2 * S + ks) * NTp + 4 * jg] = make_float4(a20,a21,a22,a23);
        *(float4*)&red[(3 * S + ks) * NTp + 4 * jg] = make_float4(a30,a31,a32,a33);
    }
    __syncthreads();

    for (int t = tid; t < 512; t += 256) {
        int b = t >> 7, u = t & 127;
        float s = (u < 64) ? b_mu[u] : b_lv[u - 64];
        #pragma unroll
        for (int si = 0; si < S; ++si) s += red[(b * S + si) * NTp + u];
        ml[b][u] = s;
        out[(u < 64 ? MU_OFF : LV_OFF) + (b0 + b) * 64 + (u & 63)] = s;
    }
    __syncthreads();
    {
        int b = tid >> 6, j = tid & 63;
        Z[(b0 + b) * 64 + j] = fmaf(eps[(b0 + b) * 64 + j],
                                    expf(0.5f * ml[b][64 + j]), ml[b][j]);
    }
}

// ---- heads (K=512, N=64 padded; 44 live) + cp scatter epilogue ----
__global__ __launch_bounds__(256) void gemm_heads(
    const float* __restrict__ A, const __hip_bfloat16* __restrict__ Wb,
    const float* __restrict__ p_b, const float* __restrict__ wd_b,
    const float* __restrict__ a_b, float* __restrict__ out)
{
    constexpr int K = 512, N = 64, JG = 16, S = 16, Ks = 32, NTp = 68, BT = 4;
    const int tid = threadIdx.x;
    const int b0  = blockIdx.x * BT;

    __shared__ __align__(16) float Atile[BT * K];
    __shared__ __align__(16) float red[BT * S * NTp];
    __shared__ float pts[BT][40];

    for (int i = tid; i < BT * K; i += 256) {
        int b = i / K, k = i - b * K;
        Atile[k * BT + b] = A[(b0 + b) * K + k];
    }
    __syncthreads();

    {
        const int jg = tid % JG, ks = tid / JG;
        const uint2* wp = (const uint2*)Wb + (ks * Ks) * (N / 4) + jg;
        const float4* xp = (const float4*)Atile + ks * Ks;
        float a00=0,a01=0,a02=0,a03=0, a10=0,a11=0,a12=0,a13=0;
        float a20=0,a21=0,a22=0,a23=0, a30=0,a31=0,a32=0,a33=0;
        #pragma unroll 4
        for (int kk = 0; kk < Ks; ++kk) {
            uint2 w = wp[kk * (N / 4)];
            float w0,w1,w2,w3; bf2(w.x,w0,w1); bf2(w.y,w2,w3);
            float4 xv = xp[kk];
            a00 = fmaf(xv.x,w0,a00); a01 = fmaf(xv.x,w1,a01);
            a02 = fmaf(xv.x,w2,a02); a03 = fmaf(xv.x,w3,a03);
            a10 = fmaf(xv.y,w0,a10); a11 = fmaf(xv.y,w1,a11);
            a12 = fmaf(xv.y,w2,a12); a13 = fmaf(xv.y,w3,a13);
            a20 = fmaf(xv.z,w0,a20); a21 = fmaf(xv.z,w1,a21);
            a22 = fmaf(xv.z,w2,a22); a23 = fmaf(xv.z,w3,a23);
            a30 = fmaf(xv.w,w0,a30); a31 = fmaf(xv.w,w1,a31);
            a32 = fmaf(xv.w,w2,a32); a33 = fmaf(xv.w,w3,a33);
        }
        *(float4*)&red[(0 * S + ks) * NTp + 4 * jg] = make_float4(a00,a01,a02,a03);
        *(float4*)&red[(1 * S + ks) * NTp + 4 * jg] = make_float4(a10,a11,a12,a13);
        *(float4*)&red[(2 * S + ks) * NTp + 4 * jg] = make_float4(a20,a21,a22,a23);
        *(float4*)&red[(3 * S + ks) * NTp + 4 * jg] = make_float4(a30,a31,a32,a33);
    }
    __syncthreads();

    {
        int b = tid >> 6, u = tid & 63;
        if (u < 44) {
            float s = 0.f;
            #pragma unroll
            for (int si = 0; si < S; ++si) s += red[(b * S + si) * NTp + u];
            if (u < 40) {
                pts[b][u] = tanhf(s + p_b[u]) * 12.f + 14.f;   // CANVAS/2-MARGIN
            } else if (u < 42) {
                out[W_OFF + (b0 + b) * 2 + (u - 40)] =
                    sigmoidf(s + wd_b[u - 40]) * 2.f + 1.f;
            } else {
                out[A_OFF + (b0 + b) * 2 + (u - 42)] = sigmoidf(s + a_b[u - 42]);
            }
        }
    }
    __syncthreads();

    if (tid < 192) {
        int bb = tid / 48, i = tid % 48;
        int p = i / 24, rem = i % 24;
        int s = rem / 8, kc = rem % 8;
        int k = kc >> 1, c = kc & 1;
        out[CP_OFF + (b0 + bb) * 48 + i] = pts[bb][p * 20 + (3 * s + k) * 2 + c];
    }
}

// ---- render: grid (128, 4), 256 threads; block (b,q) -> pixel rows 7q.. ----
__global__ __launch_bounds__(256) void vae_render(float* __restrict__ out)
{
    const int b   = blockIdx.x;
    const int q   = blockIdx.y;
    const int tid = threadIdx.x;

    __shared__ float2 cur[192];
    __shared__ float  wa[4];

    if (tid < 192) {
        int p = tid / 96;
        int m = tid % 96;
        int s = m / 32;
        int t = m % 32;
        float u  = (t + 0.5f) * (1.f / 32.f);
        float v  = 1.f - u;
        float b0 = v * v * v;
        float b1 = 3.f * u * v * v;
        float b2 = 3.f * u * u * v;
        float b3 = u * u * u;
        const float* cp = out + CP_OFF + b * 48 + p * 24 + s * 8;
        float cx = b0 * cp[0] + b1 * cp[2] + b2 * cp[4] + b3 * cp[6];
        float cy = b0 * cp[1] + b1 * cp[3] + b2 * cp[5] + b3 * cp[7];
        cur[tid] = make_float2(cx, cy);
    } else if (tid < 196) {
        int i = tid - 192;
        wa[i] = (i < 2) ? 0.5f * out[W_OFF + b * 2 + i]
                        : out[A_OFF + b * 2 + (i - 2)];
    }
    __syncthreads();

    if (tid < 196) {
        int Y = tid / 28, X = tid - Y * 28;
        float px0 = X + 0.25f;
        float py0 = (7 * q + Y) + 0.25f;

        float mA[4] = {1e30f, 1e30f, 1e30f, 1e30f};
        float mB[4] = {1e30f, 1e30f, 1e30f, 1e30f};
        #pragma unroll 4
        for (int m = 0; m < 96; ++m) {
            float2 c = cur[m];
            float dx0 = px0 - c.x, dy0 = py0 - c.y;
            float dx1 = dx0 + 0.5f, dy1 = dy0 + 0.5f;
            float xx0 = dx0 * dx0, xx1 = dx1 * dx1;
            float yy0 = dy0 * dy0, yy1 = dy1 * dy1;
            mA[0] = fminf(mA[0], xx0 + yy0);
            mA[1] = fminf(mA[1], xx1 + yy0);
            mA[2] = fminf(mA[2], xx0 + yy1);
            mA[3] = fminf(mA[3], xx1 + yy1);
        }
        #pragma unroll 4
        for (int m = 96; m < 192; ++m) {
            float2 c = cur[m];
            float dx0 = px0 - c.x, dy0 = py0 - c.y;
            float dx1 = dx0 + 0.5f, dy1 = dy0 + 0.5f;
            float xx0 = dx0 * dx0, xx1 = dx1 * dx1;
            float yy0 = dy0 * dy0, yy1 = dy1 * dy1;
            mB[0] = fminf(mB[0], xx0 + yy0);
            mB[1] = fminf(mB[1], xx1 + yy0);
            mB[2] = fminf(mB[2], xx0 + yy1);
            mB[3] = fminf(mB[3], xx1 + yy1);
        }

        const float w0 = wa[0], w1 = wa[1], a0 = wa[2], a1 = wa[3];
        float v = 0.f;
        #pragma unroll
        for (int s = 0; s < 4; ++s) {
            float d0 = sqrtf(mA[s] + 1e-12f);
            float d1 = sqrtf(mB[s] + 1e-12f);
            float c0 = a0 / (1.f + expf(-2.f * (w0 - d0)));
            float c1 = a1 / (1.f + expf(-2.f * (w1 - d1)));
            v += (1.f - c0) * (1.f - c1);
        }
        out[REND_OFF + b * 784 + (7 * q + Y) * 28 + X] = 1.f - 0.25f * v;
    }
}

extern "C" void kernel_launch(void* const* d_in, const int* in_sizes, int n_in,
                              void* d_out, int out_size, void* d_ws, size_t ws_size,
                              hipStream_t stream) {
    const float* x    = (const float*)d_in[0];
    const float* eps  = (const float*)d_in[1];
    const float* e_w1 = (const float*)d_in[2];
    const float* e_b1 = (const float*)d_in[3];
    const float* e_w2 = (const float*)d_in[4];
    const float* e_b2 = (const float*)d_in[5];
    const float* w_mu = (const float*)d_in[6];
    const float* b_mu = (const float*)d_in[7];
    const float* w_lv = (const float*)d_in[8];
    const float* b_lv = (const float*)d_in[9];
    const float* d_w1 = (const float*)d_in[10];
    const float* d_b1 = (const float*)d_in[11];
    const float* d_w2 = (const float*)d_in[12];
    const float* d_b2 = (const float*)d_in[13];
    const float* p_w  = (const float*)d_in[14];
    const float* p_b  = (const float*)d_in[15];
    const float* wd_w = (const float*)d_in[16];
    const float* wd_b = (const float*)d_in[17];
    const float* a_w  = (const float*)d_in[18];
    const float* a_b  = (const float*)d_in[19];
    float* out = (float*)d_out;
    __hip_bfloat16* ws = (__hip_bfloat16*)d_ws;
    float* wsf = (float*)((char*)d_ws + WS_TOT * 2);

    hipLaunchKernelGGL(conv_w, dim3(2448), dim3(256), 0, stream,
                       e_w1, e_w2, w_mu, w_lv, d_w1, d_w2, p_w, wd_w, a_w, ws);

    hipLaunchKernelGGL((gemm_act<784, 256, 64, 1>), dim3(4, 32), dim3(256), 0,
                       stream, x, ws + WS_W1, e_b1, wsf + AF_H1);
    hipLaunchKernelGGL((gemm_act<256, 256, 64, 1>), dim3(4, 32), dim3(256), 0,
                       stream, wsf + AF_H1, ws + WS_W2, e_b2, wsf + AF_H2);
    hipLaunchKernelGGL(gemm_ml, dim3(32), dim3(256), 0, stream,
                       wsf + AF_H2, ws + WS_ML, b_mu, b_lv, eps, out, wsf + AF_Z);
    hipLaunchKernelGGL((gemm_act<64, 512, 64, 2>), dim3(8, 32), dim3(256), 0,
                       stream, wsf + AF_Z, ws + WS_D1, d_b1, wsf + AF_D1);
    hipLaunchKernelGGL((gemm_act<512, 512, 64, 2>), dim3(8, 32), dim3(256), 0,
                       stream, wsf + AF_D1, ws + WS_D2, d_b2, wsf + AF_D2);
    hipLaunchKernelGGL(gemm_heads, dim3(32), dim3(256), 0, stream,
                       wsf + AF_D2, ws + WS_H, p_b, wd_b, a_b, out);

    hipLaunchKernelGGL(vae_render, dim3(128, 4), dim3(256), 0, stream, out);
}

// Round 5
// 125.477 us; speedup vs baseline: 1.1889x; 1.1889x over previous
//
#include <hip/hip_runtime.h>
#include <hip/hip_bf16.h>
#include <math.h>

// Output layout (float32, concatenated in reference return order):
//   rendered [128,1,28,28]  @ 0       (100352)
//   mu       [128,64]       @ 100352  (8192)
//   logvar   [128,64]       @ 108544  (8192)
//   cp       [128,2,3,4,2]  @ 116736  (6144)
//   widths   [128,2]        @ 122880  (256)
//   alphas   [128,2]        @ 123136  (256)
#define REND_OFF 0
#define MU_OFF   100352
#define LV_OFF   108544
#define CP_OFF   116736
#define W_OFF    122880
#define A_OFF    123136

// bf16 weight workspace, k-pair tiled: uint4 q at (k2, j4) holds
// { W[2k2][4j4..+3], W[2k2+1][4j4..+3] } as 8 bf16. Layer uint4 bases:
#define Q_W1 0       // [400][64]  (K padded 784->800)
#define Q_W2 25600   // [128][64]
#define Q_ML 33792   // [128][32]  (mu|lv fused, N=128)
#define Q_D1 37888   // [32][128]
#define Q_D2 41984   // [256][128]
#define Q_H  74752   // [256][16]  (p|wd|a|pad0, N=64)
#define Q_TOT 78848

__device__ __forceinline__ float leakyf(float x) {
    return x >= 0.f ? x : 0.2f * x;
}
__device__ __forceinline__ float seluf(float x) {
    const float sc = 1.0507009873554805f;
    const float al = 1.6732632423543772f;
    return x > 0.f ? sc * x : sc * al * expm1f(x);
}
__device__ __forceinline__ float sigmoidf(float x) {
    return 1.f / (1.f + expf(-x));
}
__device__ __forceinline__ void bf2(unsigned u, float& lo, float& hi) {
    lo = __uint_as_float(u << 16);
    hi = __uint_as_float(u & 0xffff0000u);
}
__device__ __forceinline__ unsigned short bfbits(float v) {
    __hip_bfloat16 h = (__hip_bfloat16)v;
    return *(unsigned short*)&h;
}

// ---- kernel 0: build k-pair-tiled bf16 weight workspace ----
__global__ __launch_bounds__(256) void conv_w(
    const float* __restrict__ e_w1, const float* __restrict__ e_w2,
    const float* __restrict__ w_mu, const float* __restrict__ w_lv,
    const float* __restrict__ d_w1, const float* __restrict__ d_w2,
    const float* __restrict__ p_w,  const float* __restrict__ wd_w,
    const float* __restrict__ a_w,  uint4* __restrict__ wsq)
{
    int t = blockIdx.x * 256 + threadIdx.x;
    if (t >= Q_TOT) return;
    float v[8];
    if (t < Q_W2) {                       // W1: [800][256], rows >=784 zero
        int q = t, k2 = q >> 6, j4 = q & 63;
        int k0 = 2 * k2, c0 = 4 * j4;
        #pragma unroll
        for (int e = 0; e < 8; ++e) {
            int k = k0 + (e >> 2), c = c0 + (e & 3);
            v[e] = (k < 784) ? e_w1[k * 256 + c] : 0.f;
        }
    } else if (t < Q_ML) {                // W2: [256][256]
        int q = t - Q_W2, k2 = q >> 6, j4 = q & 63;
        int k0 = 2 * k2, c0 = 4 * j4;
        #pragma unroll
        for (int e = 0; e < 8; ++e)
            v[e] = e_w2[(k0 + (e >> 2)) * 256 + c0 + (e & 3)];
    } else if (t < Q_D1) {                // ML: [256][128] = mu|lv
        int q = t - Q_ML, k2 = q >> 5, j4 = q & 31;
        int k0 = 2 * k2, c0 = 4 * j4;
        #pragma unroll
        for (int e = 0; e < 8; ++e) {
            int k = k0 + (e >> 2), c = c0 + (e & 3);
            v[e] = (c < 64) ? w_mu[k * 64 + c] : w_lv[k * 64 + c - 64];
        }
    } else if (t < Q_D2) {                // D1: [64][512]
        int q = t - Q_D1, k2 = q >> 7, j4 = q & 127;
        int k0 = 2 * k2, c0 = 4 * j4;
        #pragma unroll
        for (int e = 0; e < 8; ++e)
            v[e] = d_w1[(k0 + (e >> 2)) * 512 + c0 + (e & 3)];
    } else if (t < Q_H) {                 // D2: [512][512]
        int q = t - Q_D2, k2 = q >> 7, j4 = q & 127;
        int k0 = 2 * k2, c0 = 4 * j4;
        #pragma unroll
        for (int e = 0; e < 8; ++e)
            v[e] = d_w2[(k0 + (e >> 2)) * 512 + c0 + (e & 3)];
    } else {                              // H: [512][64] = p|wd|a|0
        int q = t - Q_H, k2 = q >> 4, j4 = q & 15;
        int k0 = 2 * k2, c0 = 4 * j4;
        #pragma unroll
        for (int e = 0; e < 8; ++e) {
            int k = k0 + (e >> 2), c = c0 + (e & 3);
            v[e] = (c < 40) ? p_w[k * 40 + c]
                 : (c < 42) ? wd_w[k * 2 + c - 40]
                 : (c < 44) ? a_w[k * 2 + c - 42] : 0.f;
        }
    }
    uint4 u;
    u.x = bfbits(v[0]) | ((unsigned)bfbits(v[1]) << 16);
    u.y = bfbits(v[2]) | ((unsigned)bfbits(v[3]) << 16);
    u.z = bfbits(v[4]) | ((unsigned)bfbits(v[5]) << 16);
    u.w = bfbits(v[6]) | ((unsigned)bfbits(v[7]) << 16);
    wsq[t] = u;
}

// ---- generic layer slice GEMM: 16B weight loads, b128 activation reads ----
// K2 = K/2 k-pairs, JG = N/4 col groups, S = 1024/JG k-slices, KsP pairs/thr.
template<int K2, int N, int JG, int S, int KsP>
__device__ __forceinline__ void layer_gemm(const uint4* __restrict__ wq,
                                           const float4* __restrict__ xq,
                                           float* __restrict__ red, int tid)
{
    constexpr int NTp = N + 4;
    const int jg = tid % JG, ks = tid / JG;
    const uint4* wp = wq + (ks * KsP) * (N / 4) + jg;
    const float4* xp = xq + ks * KsP;
    float a00=0,a01=0,a02=0,a03=0, a10=0,a11=0,a12=0,a13=0;
    #pragma unroll 8
    for (int kk = 0; kk < KsP; ++kk) {
        uint4 w = wp[kk * (N / 4)];
        float4 xv = xp[kk];   // {x[2k][b0], x[2k][b1], x[2k+1][b0], x[2k+1][b1]}
        float w0,w1,w2,w3,w4,w5,w6,w7;
        bf2(w.x,w0,w1); bf2(w.y,w2,w3); bf2(w.z,w4,w5); bf2(w.w,w6,w7);
        a00=fmaf(xv.x,w0,a00); a01=fmaf(xv.x,w1,a01);
        a02=fmaf(xv.x,w2,a02); a03=fmaf(xv.x,w3,a03);
        a10=fmaf(xv.y,w0,a10); a11=fmaf(xv.y,w1,a11);
        a12=fmaf(xv.y,w2,a12); a13=fmaf(xv.y,w3,a13);
        a00=fmaf(xv.z,w4,a00); a01=fmaf(xv.z,w5,a01);
        a02=fmaf(xv.z,w6,a02); a03=fmaf(xv.z,w7,a03);
        a10=fmaf(xv.w,w4,a10); a11=fmaf(xv.w,w5,a11);
        a12=fmaf(xv.w,w6,a12); a13=fmaf(xv.w,w7,a13);
    }
    *(float4*)&red[(0 * S + ks) * NTp + 4 * jg] = make_float4(a00,a01,a02,a03);
    *(float4*)&red[(1 * S + ks) * NTp + 4 * jg] = make_float4(a10,a11,a12,a13);
}

template<int N, int S, int ACT>
__device__ __forceinline__ void layer_reduce(const float* __restrict__ red,
                                             const float* __restrict__ bias,
                                             float* __restrict__ Cint, int tid)
{
    constexpr int NTp = N + 4;
    if (tid < 2 * N) {
        int b = tid / N, j = tid % N;
        float s = bias[j];
        #pragma unroll
        for (int si = 0; si < S; ++si) s += red[(b * S + si) * NTp + j];
        s = (ACT == 1) ? leakyf(s) : seluf(s);
        Cint[j * 2 + b] = s;
    }
}

// ---- fused MLP: 64 blocks x 1024 thr; 2 batch elems per block ----
__global__ __launch_bounds__(1024) void vae_mlp(
    const float* __restrict__ x,    const float* __restrict__ eps,
    const float* __restrict__ e_b1, const float* __restrict__ e_b2,
    const float* __restrict__ b_mu, const float* __restrict__ b_lv,
    const float* __restrict__ d_b1, const float* __restrict__ d_b2,
    const float* __restrict__ p_b,  const float* __restrict__ wd_b,
    const float* __restrict__ a_b,
    const uint4* __restrict__ wsq,  float* __restrict__ out)
{
    const int b0  = blockIdx.x * 2;
    const int tid = threadIdx.x;

    __shared__ __align__(16) float xs[1600];    // [k][b], K padded to 800
    __shared__ __align__(16) float h1i[512];    // [k][b]
    __shared__ __align__(16) float h2i[512];
    __shared__ __align__(16) float zsi[128];
    __shared__ __align__(16) float hd1i[1024];
    __shared__ __align__(16) float hd2i[1024];
    __shared__ float mulv[2][128];
    __shared__ float pts[2][40];
    __shared__ __align__(16) float red[8704];   // max: heads 2*64*68

    for (int i = tid; i < 1600; i += 1024) {
        int k = i >> 1, b = i & 1;
        xs[i] = (k < 784) ? x[(b0 + b) * 784 + k] : 0.f;
    }
    __syncthreads();

    // encoder L1: K=800(pad), N=256
    layer_gemm<400, 256, 64, 16, 25>(wsq + Q_W1, (const float4*)xs, red, tid);
    __syncthreads();
    layer_reduce<256, 16, 1>(red, e_b1, h1i, tid);
    __syncthreads();

    // encoder L2: K=256, N=256
    layer_gemm<128, 256, 64, 16, 8>(wsq + Q_W2, (const float4*)h1i, red, tid);
    __syncthreads();
    layer_reduce<256, 16, 1>(red, e_b2, h2i, tid);
    __syncthreads();

    // mu|logvar: K=256, N=128 + reparameterization
    layer_gemm<128, 128, 32, 32, 4>(wsq + Q_ML, (const float4*)h2i, red, tid);
    __syncthreads();
    if (tid < 256) {
        int b = tid >> 7, u = tid & 127;
        float s = (u < 64) ? b_mu[u] : b_lv[u - 64];
        #pragma unroll
        for (int si = 0; si < 32; ++si) s += red[(b * 32 + si) * 132 + u];
        mulv[b][u] = s;
        out[(u < 64 ? MU_OFF : LV_OFF) + (b0 + b) * 64 + (u & 63)] = s;
    }
    __syncthreads();
    if (tid < 128) {
        int b = tid >> 6, j = tid & 63;
        zsi[j * 2 + b] = fmaf(eps[(b0 + b) * 64 + j],
                              expf(0.5f * mulv[b][64 + j]), mulv[b][j]);
    }
    __syncthreads();

    // decoder L1: K=64, N=512
    layer_gemm<32, 512, 128, 8, 4>(wsq + Q_D1, (const float4*)zsi, red, tid);
    __syncthreads();
    layer_reduce<512, 8, 2>(red, d_b1, hd1i, tid);
    __syncthreads();

    // decoder L2: K=512, N=512
    layer_gemm<256, 512, 128, 8, 32>(wsq + Q_D2, (const float4*)hd1i, red, tid);
    __syncthreads();
    layer_reduce<512, 8, 2>(red, d_b2, hd2i, tid);
    __syncthreads();

    // heads: K=512, N=64 (44 live)
    layer_gemm<256, 64, 16, 64, 4>(wsq + Q_H, (const float4*)hd2i, red, tid);
    __syncthreads();
    if (tid < 128) {
        int b = tid >> 6, u = tid & 63;
        if (u < 44) {
            float s = 0.f;
            #pragma unroll
            for (int si = 0; si < 64; ++si) s += red[(b * 64 + si) * 68 + u];
            if (u < 40) {
                pts[b][u] = tanhf(s + p_b[u]) * 12.f + 14.f;  // CANVAS/2-MARGIN
            } else if (u < 42) {
                out[W_OFF + (b0 + b) * 2 + (u - 40)] =
                    sigmoidf(s + wd_b[u - 40]) * 2.f + 1.f;
            } else {
                out[A_OFF + (b0 + b) * 2 + (u - 42)] = sigmoidf(s + a_b[u - 42]);
            }
        }
    }
    __syncthreads();

    // scatter cp [P=2,S=3,4,2] from pts [P=2,PPP=10,2]
    if (tid < 96) {
        int bs = tid / 48, i = tid % 48;
        int p = i / 24, rem = i % 24;
        int s = rem / 8, kc = rem % 8;
        int k = kc >> 1, c = kc & 1;
        out[CP_OFF + (b0 + bs) * 48 + i] = pts[bs][p * 20 + (3 * s + k) * 2 + c];
    }
}

// ---- render: grid (128, 4), 256 threads; block (b,q) -> pixel rows 7q.. ----
__global__ __launch_bounds__(256) void vae_render(float* __restrict__ out)
{
    const int b   = blockIdx.x;
    const int q   = blockIdx.y;
    const int tid = threadIdx.x;

    __shared__ float2 cur[192];
    __shared__ float  wa[4];

    if (tid < 192) {
        int p = tid / 96;
        int m = tid % 96;
        int s = m / 32;
        int t = m % 32;
        float u  = (t + 0.5f) * (1.f / 32.f);
        float v  = 1.f - u;
        float b0 = v * v * v;
        float b1 = 3.f * u * v * v;
        float b2 = 3.f * u * u * v;
        float b3 = u * u * u;
        const float* cp = out + CP_OFF + b * 48 + p * 24 + s * 8;
        float cx = b0 * cp[0] + b1 * cp[2] + b2 * cp[4] + b3 * cp[6];
        float cy = b0 * cp[1] + b1 * cp[3] + b2 * cp[5] + b3 * cp[7];
        cur[tid] = make_float2(cx, cy);
    } else if (tid < 196) {
        int i = tid - 192;
        wa[i] = (i < 2) ? 0.5f * out[W_OFF + b * 2 + i]
                        : out[A_OFF + b * 2 + (i - 2)];
    }
    __syncthreads();

    if (tid < 196) {
        int Y = tid / 28, X = tid - Y * 28;
        float px0 = X + 0.25f;
        float py0 = (7 * q + Y) + 0.25f;

        float mA[4] = {1e30f, 1e30f, 1e30f, 1e30f};
        float mB[4] = {1e30f, 1e30f, 1e30f, 1e30f};
        #pragma unroll 4
        for (int m = 0; m < 96; ++m) {
            float2 c = cur[m];
            float dx0 = px0 - c.x, dy0 = py0 - c.y;
            float dx1 = dx0 + 0.5f, dy1 = dy0 + 0.5f;
            float xx0 = dx0 * dx0, xx1 = dx1 * dx1;
            float yy0 = dy0 * dy0, yy1 = dy1 * dy1;
            mA[0] = fminf(mA[0], xx0 + yy0);
            mA[1] = fminf(mA[1], xx1 + yy0);
            mA[2] = fminf(mA[2], xx0 + yy1);
            mA[3] = fminf(mA[3], xx1 + yy1);
        }
        #pragma unroll 4
        for (int m = 96; m < 192; ++m) {
            float2 c = cur[m];
            float dx0 = px0 - c.x, dy0 = py0 - c.y;
            float dx1 = dx0 + 0.5f, dy1 = dy0 + 0.5f;
            float xx0 = dx0 * dx0, xx1 = dx1 * dx1;
            float yy0 = dy0 * dy0, yy1 = dy1 * dy1;
            mB[0] = fminf(mB[0], xx0 + yy0);
            mB[1] = fminf(mB[1], xx1 + yy0);
            mB[2] = fminf(mB[2], xx0 + yy1);
            mB[3] = fminf(mB[3], xx1 + yy1);
        }

        const float w0 = wa[0], w1 = wa[1], a0 = wa[2], a1 = wa[3];
        float v = 0.f;
        #pragma unroll
        for (int s = 0; s < 4; ++s) {
            float d0 = sqrtf(mA[s] + 1e-12f);
            float d1 = sqrtf(mB[s] + 1e-12f);
            float c0 = a0 / (1.f + expf(-2.f * (w0 - d0)));
            float c1 = a1 / (1.f + expf(-2.f * (w1 - d1)));
            v += (1.f - c0) * (1.f - c1);
        }
        out[REND_OFF + b * 784 + (7 * q + Y) * 28 + X] = 1.f - 0.25f * v;
    }
}

extern "C" void kernel_launch(void* const* d_in, const int* in_sizes, int n_in,
                              void* d_out, int out_size, void* d_ws, size_t ws_size,
                              hipStream_t stream) {
    const float* x    = (const float*)d_in[0];
    const float* eps  = (const float*)d_in[1];
    const float* e_w1 = (const float*)d_in[2];
    const float* e_b1 = (const float*)d_in[3];
    const float* e_w2 = (const float*)d_in[4];
    const float* e_b2 = (const float*)d_in[5];
    const float* w_mu = (const float*)d_in[6];
    const float* b_mu = (const float*)d_in[7];
    const float* w_lv = (const float*)d_in[8];
    const float* b_lv = (const float*)d_in[9];
    const float* d_w1 = (const float*)d_in[10];
    const float* d_b1 = (const float*)d_in[11];
    const float* d_w2 = (const float*)d_in[12];
    const float* d_b2 = (const float*)d_in[13];
    const float* p_w  = (const float*)d_in[14];
    const float* p_b  = (const float*)d_in[15];
    const float* wd_w = (const float*)d_in[16];
    const float* wd_b = (const float*)d_in[17];
    const float* a_w  = (const float*)d_in[18];
    const float* a_b  = (const float*)d_in[19];
    float* out = (float*)d_out;
    uint4* wsq = (uint4*)d_ws;

    hipLaunchKernelGGL(conv_w, dim3((Q_TOT + 255) / 256), dim3(256), 0, stream,
                       e_w1, e_w2, w_mu, w_lv, d_w1, d_w2, p_w, wd_w, a_w, wsq);
    hipLaunchKernelGGL(vae_mlp, dim3(64), dim3(1024), 0, stream,
                       x, eps, e_b1, e_b2, b_mu, b_lv, d_b1, d_b2,
                       p_b, wd_b, a_b, wsq, out);
    hipLaunchKernelGGL(vae_render, dim3(128, 4), dim3(256), 0, stream, out);
}

// Round 6
// 122.853 us; speedup vs baseline: 1.2143x; 1.0214x over previous
//
#include <hip/hip_runtime.h>
#include <hip/hip_bf16.h>
#include <hip/hip_fp16.h>
#include <math.h>

// Output layout (float32, concatenated in reference return order):
//   rendered [128,1,28,28]  @ 0       (100352)
//   mu       [128,64]       @ 100352  (8192)
//   logvar   [128,64]       @ 108544  (8192)
//   cp       [128,2,3,4,2]  @ 116736  (6144)
//   widths   [128,2]        @ 122880  (256)
//   alphas   [128,2]        @ 123136  (256)
#define REND_OFF 0
#define MU_OFF   100352
#define LV_OFF   108544
#define CP_OFF   116736
#define W_OFF    122880
#define A_OFF    123136

// fp16 weight workspace, k-pair COLUMN packed for v_dot2_f32_f16:
// uint4 q at (k2, j4): q.x = {W[2k2][4j4], W[2k2+1][4j4]} as half2, q.y..q.w
// the next 3 columns. Layer uint4 bases (element counts unchanged from r5):
#define Q_W1 0       // [400][64]  (K padded 784->800)
#define Q_W2 25600   // [128][64]
#define Q_ML 33792   // [128][32]  (mu|lv fused, N=128)
#define Q_D1 37888   // [32][128]
#define Q_D2 41984   // [256][128]
#define Q_H  74752   // [256][16]  (p|wd|a|pad0, N=64)
#define Q_TOT 78848

typedef _Float16 half2_t __attribute__((ext_vector_type(2)));

__device__ __forceinline__ float leakyf(float x) {
    return x >= 0.f ? x : 0.2f * x;
}
__device__ __forceinline__ float seluf(float x) {
    const float sc = 1.0507009873554805f;
    const float al = 1.6732632423543772f;
    return x > 0.f ? sc * x : sc * al * expm1f(x);
}
__device__ __forceinline__ float sigmoidf(float x) {
    return 1.f / (1.f + expf(-x));
}
__device__ __forceinline__ unsigned pkh(float a, float b) {
    __half ha = __float2half(a), hb = __float2half(b);
    return (unsigned)__half_as_ushort(ha) | ((unsigned)__half_as_ushort(hb) << 16);
}
__device__ __forceinline__ half2_t as_h2(unsigned u) {
    union { unsigned u; half2_t h; } c; c.u = u; return c.h;
}
__device__ __forceinline__ float dot2(unsigned a, unsigned w, float acc) {
#if __has_builtin(__builtin_amdgcn_fdot2)
    return __builtin_amdgcn_fdot2(as_h2(a), as_h2(w), acc, false);
#else
    half2_t ah = as_h2(a), wh = as_h2(w);
    acc = fmaf((float)ah[0], (float)wh[0], acc);
    return fmaf((float)ah[1], (float)wh[1], acc);
#endif
}

// ---- kernel 0: build k-pair column-packed fp16 weight workspace ----
__global__ __launch_bounds__(256) void conv_w(
    const float* __restrict__ e_w1, const float* __restrict__ e_w2,
    const float* __restrict__ w_mu, const float* __restrict__ w_lv,
    const float* __restrict__ d_w1, const float* __restrict__ d_w2,
    const float* __restrict__ p_w,  const float* __restrict__ wd_w,
    const float* __restrict__ a_w,  uint4* __restrict__ wsq)
{
    int t = blockIdx.x * 256 + threadIdx.x;
    if (t >= Q_TOT) return;
    float lo[4], hi[4];
    if (t < Q_W2) {                       // W1: [800pad][256]
        int q = t, k2 = q >> 6, j4 = q & 63;
        int k0 = 2 * k2, c0 = 4 * j4;
        #pragma unroll
        for (int c = 0; c < 4; ++c) {
            lo[c] = (k0     < 784) ? e_w1[k0 * 256 + c0 + c] : 0.f;
            hi[c] = (k0 + 1 < 784) ? e_w1[(k0 + 1) * 256 + c0 + c] : 0.f;
        }
    } else if (t < Q_ML) {                // W2: [256][256]
        int q = t - Q_W2, k2 = q >> 6, j4 = q & 63;
        int k0 = 2 * k2, c0 = 4 * j4;
        #pragma unroll
        for (int c = 0; c < 4; ++c) {
            lo[c] = e_w2[k0 * 256 + c0 + c];
            hi[c] = e_w2[(k0 + 1) * 256 + c0 + c];
        }
    } else if (t < Q_D1) {                // ML: [256][128] = mu|lv
        int q = t - Q_ML, k2 = q >> 5, j4 = q & 31;
        int k0 = 2 * k2, c0 = 4 * j4;
        #pragma unroll
        for (int c = 0; c < 4; ++c) {
            int cc = c0 + c;
            lo[c] = (cc < 64) ? w_mu[k0 * 64 + cc] : w_lv[k0 * 64 + cc - 64];
            hi[c] = (cc < 64) ? w_mu[(k0 + 1) * 64 + cc]
                              : w_lv[(k0 + 1) * 64 + cc - 64];
        }
    } else if (t < Q_D2) {                // D1: [64][512]
        int q = t - Q_D1, k2 = q >> 7, j4 = q & 127;
        int k0 = 2 * k2, c0 = 4 * j4;
        #pragma unroll
        for (int c = 0; c < 4; ++c) {
            lo[c] = d_w1[k0 * 512 + c0 + c];
            hi[c] = d_w1[(k0 + 1) * 512 + c0 + c];
        }
    } else if (t < Q_H) {                 // D2: [512][512]
        int q = t - Q_D2, k2 = q >> 7, j4 = q & 127;
        int k0 = 2 * k2, c0 = 4 * j4;
        #pragma unroll
        for (int c = 0; c < 4; ++c) {
            lo[c] = d_w2[k0 * 512 + c0 + c];
            hi[c] = d_w2[(k0 + 1) * 512 + c0 + c];
        }
    } else {                              // H: [512][64] = p|wd|a|0
        int q = t - Q_H, k2 = q >> 4, j4 = q & 15;
        int k0 = 2 * k2, c0 = 4 * j4;
        #pragma unroll
        for (int c = 0; c < 4; ++c) {
            int cc = c0 + c;
            lo[c] = (cc < 40) ? p_w[k0 * 40 + cc]
                  : (cc < 42) ? wd_w[k0 * 2 + cc - 40]
                  : (cc < 44) ? a_w[k0 * 2 + cc - 42] : 0.f;
            hi[c] = (cc < 40) ? p_w[(k0 + 1) * 40 + cc]
                  : (cc < 42) ? wd_w[(k0 + 1) * 2 + cc - 40]
                  : (cc < 44) ? a_w[(k0 + 1) * 2 + cc - 42] : 0.f;
        }
    }
    uint4 u;
    u.x = pkh(lo[0], hi[0]);
    u.y = pkh(lo[1], hi[1]);
    u.z = pkh(lo[2], hi[2]);
    u.w = pkh(lo[3], hi[3]);
    wsq[t] = u;
}

// ---- layer slice GEMM via v_dot2_f32_f16: 16B weight loads, b32 act ----
// N cols, JG = N/4 col groups, S = 1024/JG k-slices, Ks k-pairs per thread.
template<int N, int JG, int S, int Ks>
__device__ __forceinline__ void hgemm(const uint4* __restrict__ wq,
                                      const unsigned* __restrict__ xu,
                                      float* __restrict__ red, int tid)
{
    constexpr int NTp = N + 4;
    const int jg = tid % JG, ks = tid / JG;
    const uint4* wp = wq + (ks * Ks) * (N / 4) + jg;
    const unsigned* xp = xu + ks * Ks;
    float a0 = 0.f, a1 = 0.f, a2 = 0.f, a3 = 0.f;
    #pragma unroll 8
    for (int kk = 0; kk < Ks; ++kk) {
        uint4 w = wp[kk * (N / 4)];
        unsigned av = xp[kk];
        a0 = dot2(av, w.x, a0);
        a1 = dot2(av, w.y, a1);
        a2 = dot2(av, w.z, a2);
        a3 = dot2(av, w.w, a3);
    }
    *(float4*)&red[ks * NTp + 4 * jg] = make_float4(a0, a1, a2, a3);
}

// reduce S slices, apply act, pack adjacent unit pairs to half2
template<int N, int S, int ACT>
__device__ __forceinline__ void reduce_pack(const float* __restrict__ red,
                                            const float* __restrict__ bias,
                                            unsigned* __restrict__ Cu, int tid)
{
    constexpr int NTp = N + 4;
    if (tid < N / 2) {
        int j0 = 2 * tid;
        float s0 = bias[j0], s1 = bias[j0 + 1];
        #pragma unroll
        for (int si = 0; si < S; ++si) {
            s0 += red[si * NTp + j0];
            s1 += red[si * NTp + j0 + 1];
        }
        if (ACT == 1) { s0 = leakyf(s0); s1 = leakyf(s1); }
        else          { s0 = seluf(s0);  s1 = seluf(s1);  }
        Cu[tid] = pkh(s0, s1);
    }
}

// ---- fused MLP: 128 blocks x 1024 thr; 1 batch elem per block ----
__global__ __launch_bounds__(1024) void vae_mlp(
    const float* __restrict__ x,    const float* __restrict__ eps,
    const float* __restrict__ e_b1, const float* __restrict__ e_b2,
    const float* __restrict__ b_mu, const float* __restrict__ b_lv,
    const float* __restrict__ d_b1, const float* __restrict__ d_b2,
    const float* __restrict__ p_b,  const float* __restrict__ wd_b,
    const float* __restrict__ a_b,
    const uint4* __restrict__ wsq,  float* __restrict__ out)
{
    const int b   = blockIdx.x;
    const int tid = threadIdx.x;

    __shared__ __align__(16) unsigned xs[400];    // packed half2 along k
    __shared__ __align__(16) unsigned h1u[128];
    __shared__ __align__(16) unsigned h2u[128];
    __shared__ __align__(16) unsigned zu[32];
    __shared__ __align__(16) unsigned d1u[256];
    __shared__ __align__(16) unsigned d2u[256];
    __shared__ float mulv[128];
    __shared__ float pts[40];
    __shared__ __align__(16) float red[4352];     // max: heads 64*68

    if (tid < 400) {
        int k0 = 2 * tid;
        float x0 = (k0     < 784) ? x[b * 784 + k0] : 0.f;
        float x1 = (k0 + 1 < 784) ? x[b * 784 + k0 + 1] : 0.f;
        xs[tid] = pkh(x0, x1);
    }
    __syncthreads();

    // encoder L1: K=800(pad), N=256
    hgemm<256, 64, 16, 25>(wsq + Q_W1, xs, red, tid);
    __syncthreads();
    reduce_pack<256, 16, 1>(red, e_b1, h1u, tid);
    __syncthreads();

    // encoder L2: K=256, N=256
    hgemm<256, 64, 16, 8>(wsq + Q_W2, h1u, red, tid);
    __syncthreads();
    reduce_pack<256, 16, 1>(red, e_b2, h2u, tid);
    __syncthreads();

    // mu|logvar: K=256, N=128 (pairs never straddle the mu/lv split at 64)
    hgemm<128, 32, 32, 4>(wsq + Q_ML, h2u, red, tid);
    __syncthreads();
    if (tid < 64) {
        int u0 = 2 * tid;
        float s0 = (u0 < 64) ? b_mu[u0] : b_lv[u0 - 64];
        float s1 = (u0 < 64) ? b_mu[u0 + 1] : b_lv[u0 + 1 - 64];
        #pragma unroll
        for (int si = 0; si < 32; ++si) {
            s0 += red[si * 132 + u0];
            s1 += red[si * 132 + u0 + 1];
        }
        mulv[u0] = s0; mulv[u0 + 1] = s1;
        int base = (u0 < 64) ? MU_OFF : LV_OFF;
        out[base + b * 64 + (u0 & 63)]     = s0;
        out[base + b * 64 + (u0 & 63) + 1] = s1;
    }
    __syncthreads();
    if (tid < 32) {
        int j0 = 2 * tid;
        float z0 = fmaf(eps[b * 64 + j0],     expf(0.5f * mulv[64 + j0]),     mulv[j0]);
        float z1 = fmaf(eps[b * 64 + j0 + 1], expf(0.5f * mulv[64 + j0 + 1]), mulv[j0 + 1]);
        zu[tid] = pkh(z0, z1);
    }
    __syncthreads();

    // decoder L1: K=64, N=512
    hgemm<512, 128, 8, 4>(wsq + Q_D1, zu, red, tid);
    __syncthreads();
    reduce_pack<512, 8, 2>(red, d_b1, d1u, tid);
    __syncthreads();

    // decoder L2: K=512, N=512
    hgemm<512, 128, 8, 32>(wsq + Q_D2, d1u, red, tid);
    __syncthreads();
    reduce_pack<512, 8, 2>(red, d_b2, d2u, tid);
    __syncthreads();

    // heads: K=512, N=64 (44 live)
    hgemm<64, 16, 64, 4>(wsq + Q_H, d2u, red, tid);
    __syncthreads();
    if (tid < 44) {
        float s = 0.f;
        #pragma unroll
        for (int si = 0; si < 64; ++si) s += red[si * 68 + tid];
        if (tid < 40) {
            pts[tid] = tanhf(s + p_b[tid]) * 12.f + 14.f;   // CANVAS/2-MARGIN
        } else if (tid < 42) {
            out[W_OFF + b * 2 + (tid - 40)] =
                sigmoidf(s + wd_b[tid - 40]) * 2.f + 1.f;
        } else {
            out[A_OFF + b * 2 + (tid - 42)] = sigmoidf(s + a_b[tid - 42]);
        }
    }
    __syncthreads();

    // scatter cp [P=2,S=3,4,2] from pts [P=2,PPP=10,2]
    if (tid < 48) {
        int p = tid / 24, rem = tid % 24;
        int s = rem / 8, kc = rem % 8;
        int k = kc >> 1, c = kc & 1;
        out[CP_OFF + b * 48 + tid] = pts[p * 20 + (3 * s + k) * 2 + c];
    }
}

// ---- render: grid (128, 4), 256 threads; block (b,q) -> pixel rows 7q.. ----
__global__ __launch_bounds__(256) void vae_render(float* __restrict__ out)
{
    const int b   = blockIdx.x;
    const int q   = blockIdx.y;
    const int tid = threadIdx.x;

    __shared__ float2 cur[192];
    __shared__ float  wa[4];

    if (tid < 192) {
        int p = tid / 96;
        int m = tid % 96;
        int s = m / 32;
        int t = m % 32;
        float u  = (t + 0.5f) * (1.f / 32.f);
        float v  = 1.f - u;
        float b0 = v * v * v;
        float b1 = 3.f * u * v * v;
        float b2 = 3.f * u * u * v;
        float b3 = u * u * u;
        const float* cp = out + CP_OFF + b * 48 + p * 24 + s * 8;
        float cx = b0 * cp[0] + b1 * cp[2] + b2 * cp[4] + b3 * cp[6];
        float cy = b0 * cp[1] + b1 * cp[3] + b2 * cp[5] + b3 * cp[7];
        cur[tid] = make_float2(cx, cy);
    } else if (tid < 196) {
        int i = tid - 192;
        wa[i] = (i < 2) ? 0.5f * out[W_OFF + b * 2 + i]
                        : out[A_OFF + b * 2 + (i - 2)];
    }
    __syncthreads();

    if (tid < 196) {
        int Y = tid / 28, X = tid - Y * 28;
        float px0 = X + 0.25f;
        float py0 = (7 * q + Y) + 0.25f;

        float mA[4] = {1e30f, 1e30f, 1e30f, 1e30f};
        float mB[4] = {1e30f, 1e30f, 1e30f, 1e30f};
        #pragma unroll 4
        for (int m = 0; m < 96; ++m) {
            float2 c = cur[m];
            float dx0 = px0 - c.x, dy0 = py0 - c.y;
            float dx1 = dx0 + 0.5f, dy1 = dy0 + 0.5f;
            float xx0 = dx0 * dx0, xx1 = dx1 * dx1;
            float yy0 = dy0 * dy0, yy1 = dy1 * dy1;
            mA[0] = fminf(mA[0], xx0 + yy0);
            mA[1] = fminf(mA[1], xx1 + yy0);
            mA[2] = fminf(mA[2], xx0 + yy1);
            mA[3] = fminf(mA[3], xx1 + yy1);
        }
        #pragma unroll 4
        for (int m = 96; m < 192; ++m) {
            float2 c = cur[m];
            float dx0 = px0 - c.x, dy0 = py0 - c.y;
            float dx1 = dx0 + 0.5f, dy1 = dy0 + 0.5f;
            float xx0 = dx0 * dx0, xx1 = dx1 * dx1;
            float yy0 = dy0 * dy0, yy1 = dy1 * dy1;
            mB[0] = fminf(mB[0], xx0 + yy0);
            mB[1] = fminf(mB[1], xx1 + yy0);
            mB[2] = fminf(mB[2], xx0 + yy1);
            mB[3] = fminf(mB[3], xx1 + yy1);
        }

        const float w0 = wa[0], w1 = wa[1], a0 = wa[2], a1 = wa[3];
        float v = 0.f;
        #pragma unroll
        for (int s = 0; s < 4; ++s) {
            float d0 = sqrtf(mA[s] + 1e-12f);
            float d1 = sqrtf(mB[s] + 1e-12f);
            float c0 = a0 / (1.f + expf(-2.f * (w0 - d0)));
            float c1 = a1 / (1.f + expf(-2.f * (w1 - d1)));
            v += (1.f - c0) * (1.f - c1);
        }
        out[REND_OFF + b * 784 + (7 * q + Y) * 28 + X] = 1.f - 0.25f * v;
    }
}

extern "C" void kernel_launch(void* const* d_in, const int* in_sizes, int n_in,
                              void* d_out, int out_size, void* d_ws, size_t ws_size,
                              hipStream_t stream) {
    const float* x    = (const float*)d_in[0];
    const float* eps  = (const float*)d_in[1];
    const float* e_w1 = (const float*)d_in[2];
    const float* e_b1 = (const float*)d_in[3];
    const float* e_w2 = (const float*)d_in[4];
    const float* e_b2 = (const float*)d_in[5];
    const float* w_mu = (const float*)d_in[6];
    const float* b_mu = (const float*)d_in[7];
    const float* w_lv = (const float*)d_in[8];
    const float* b_lv = (const float*)d_in[9];
    const float* d_w1 = (const float*)d_in[10];
    const float* d_b1 = (const float*)d_in[11];
    const float* d_w2 = (const float*)d_in[12];
    const float* d_b2 = (const float*)d_in[13];
    const float* p_w  = (const float*)d_in[14];
    const float* p_b  = (const float*)d_in[15];
    const float* wd_w = (const float*)d_in[16];
    const float* wd_b = (const float*)d_in[17];
    const float* a_w  = (const float*)d_in[18];
    const float* a_b  = (const float*)d_in[19];
    float* out = (float*)d_out;
    uint4* wsq = (uint4*)d_ws;

    hipLaunchKernelGGL(conv_w, dim3((Q_TOT + 255) / 256), dim3(256), 0, stream,
                       e_w1, e_w2, w_mu, w_lv, d_w1, d_w2, p_w, wd_w, a_w, wsq);
    hipLaunchKernelGGL(vae_mlp, dim3(128), dim3(1024), 0, stream,
                       x, eps, e_b1, e_b2, b_mu, b_lv, d_b1, d_b2,
                       p_b, wd_b, a_b, wsq, out);
    hipLaunchKernelGGL(vae_render, dim3(128, 4), dim3(256), 0, stream, out);
}